// Round 13
// baseline (493.979 us; speedup 1.0000x reference)
//
#include <hip/hip_runtime.h>
#include <hip/hip_bf16.h>

typedef unsigned short u16;
typedef short bf16x8 __attribute__((ext_vector_type(8)));
typedef float f32x4 __attribute__((ext_vector_type(4)));
typedef float f32x16 __attribute__((ext_vector_type(16)));
typedef unsigned short u16x4 __attribute__((ext_vector_type(4)));
typedef unsigned u32x4 __attribute__((ext_vector_type(4)));

// scores pre-scaled by log2(e)/8 (folded into Wq, bq) so softmax is pure exp2
#define SCALE_Q 0.18033688011112042f

__device__ __forceinline__ u16 f2b(float f) {
    __hip_bfloat16 h = __float2bfloat16(f);   // hw v_cvt (RNE) on gfx950
    return *reinterpret_cast<u16*>(&h);
}

__device__ __forceinline__ unsigned cvt_pk_bf16(float lo, float hi) {
    unsigned r;
    asm("v_cvt_pk_bf16_f32 %0, %1, %2" : "=v"(r) : "v"(lo), "v"(hi));
    return r;
}

// single-instruction exp2/rcp via BUILTINS (hazard-safe; R10's inline-asm
// version defeated TRANS wait-state insertion -> wrong values)
#define hw_exp2 __builtin_amdgcn_exp2f
#define hw_rcp  __builtin_amdgcn_rcpf

__device__ __forceinline__ void load_lds16(const void* g, void* l) {
    __builtin_amdgcn_global_load_lds(
        (const __attribute__((address_space(1))) void*)g,
        (__attribute__((address_space(3))) void*)l, 16, 0, 0);
}

// ---------------- prep: hidden * channel_importance -> bf16 ----------------
__global__ __launch_bounds__(256) void prep_hidden(
    const float* __restrict__ x, const float* __restrict__ ci, u16* __restrict__ hbuf) {
    size_t i = ((size_t)blockIdx.x * 256 + threadIdx.x) * 4;
    float4 v = *(const float4*)(x + i);
    int c = (int)(i % 768);
    u16x4 o;
    o.x = f2b(v.x * ci[c]);     o.y = f2b(v.y * ci[c + 1]);
    o.z = f2b(v.z * ci[c + 2]); o.w = f2b(v.w * ci[c + 3]);
    *(u16x4*)(hbuf + i) = o;
}

// ---------------- prep: transpose weights to [N][K] bf16 ----------------
__global__ __launch_bounds__(256) void transpose_w(
    const float* __restrict__ Wq, const float* __restrict__ Wk,
    const float* __restrict__ Wv, const float* __restrict__ Wo,
    const float* __restrict__ cc, u16* __restrict__ wqkvt, u16* __restrict__ wot) {
    __shared__ float tile[32][33];
    int z = blockIdx.z;
    const float* src = (z == 0) ? Wq : (z == 1) ? Wk : (z == 2) ? Wv : Wo;
    u16* dst = (z < 3) ? (wqkvt + (size_t)z * 768 * 768) : wot;
    int tx = threadIdx.x & 31, ty = threadIdx.x >> 5;
    int k0 = blockIdx.x * 32, n0 = blockIdx.y * 32;
    #pragma unroll
    for (int i = ty; i < 32; i += 8) {
        float v = src[(size_t)(k0 + i) * 768 + n0 + tx];
        if (z == 3) v *= cc[k0 + i];
        if (z == 0) v *= SCALE_Q;
        tile[i][tx] = v;
    }
    __syncthreads();
    #pragma unroll
    for (int i = ty; i < 32; i += 8)
        dst[(size_t)(n0 + i) * 768 + k0 + tx] = f2b(tile[tx][i]);
}

__global__ __launch_bounds__(256) void bias_cat(
    const float* __restrict__ bq, const float* __restrict__ bk,
    const float* __restrict__ bv, float* __restrict__ biasq) {
    int i = blockIdx.x * 256 + threadIdx.x;
    biasq[i] = (i < 768) ? bq[i] * SCALE_Q : (i < 1536) ? bk[i - 768] : bv[i - 1536];
}

// ---------------- GEMM: C[M][N] = A[M][K] @ Bt[N][K]^T + bias ----------------
template <int F32OUT>
__global__ __launch_bounds__(256) void gemm_bt(
    const u16* __restrict__ A, const u16* __restrict__ Bt,
    const float* __restrict__ bias, void* __restrict__ Cout,
    int M, int N, int K, int NTN) {
    __shared__ u16 lA[128 * 64];
    __shared__ u16 lB[128 * 64];
    int nwg = gridDim.x;
    int bid = blockIdx.x;
    int wg = ((nwg & 7) == 0) ? ((bid & 7) * (nwg >> 3) + (bid >> 3)) : bid;
    int mt = wg / NTN, nt = wg % NTN;
    int row0 = mt << 7, col0 = nt << 7;
    int tid = threadIdx.x;
    int lane = tid & 63, wv = tid >> 6;
    int wm = (wv >> 1) * 64, wn = (wv & 1) * 64;
    int l15 = lane & 15, hi = lane >> 4;

    f32x4 acc[4][4] = {};

    for (int kt = 0; kt < K; kt += 64) {
        __syncthreads();
        #pragma unroll
        for (int p = 0; p < 4; ++p) {
            int cl = p * 256 + tid;
            int rr = cl >> 3;
            int cc = (cl & 7) ^ (rr & 7);
            int lo = (p * 256 + (wv << 6)) << 3;
            load_lds16(A + (size_t)(row0 + rr) * K + kt + cc * 8, &lA[lo]);
            load_lds16(Bt + (size_t)(col0 + rr) * K + kt + cc * 8, &lB[lo]);
        }
        __syncthreads();
        __builtin_amdgcn_s_setprio(1);
        #pragma unroll
        for (int ks = 0; ks < 2; ++ks) {
            bf16x8 af[4], bf[4];
            #pragma unroll
            for (int i = 0; i < 4; ++i) {
                int ra = wm + i * 16 + l15;
                af[i] = *(const bf16x8*)&lA[ra * 64 + (((ks << 2) + hi) ^ (ra & 7)) * 8];
                int rb = wn + i * 16 + l15;
                bf[i] = *(const bf16x8*)&lB[rb * 64 + (((ks << 2) + hi) ^ (rb & 7)) * 8];
            }
            #pragma unroll
            for (int mi = 0; mi < 4; ++mi)
                #pragma unroll
                for (int ni = 0; ni < 4; ++ni)
                    acc[mi][ni] = __builtin_amdgcn_mfma_f32_16x16x32_bf16(
                        af[mi], bf[ni], acc[mi][ni], 0, 0, 0);
        }
        __builtin_amdgcn_s_setprio(0);
    }

    #pragma unroll
    for (int mi = 0; mi < 4; ++mi) {
        int rbase = row0 + wm + mi * 16 + hi * 4;
        #pragma unroll
        for (int ni = 0; ni < 4; ++ni) {
            int c = col0 + wn + ni * 16 + l15;
            float bv = bias[c];
            #pragma unroll
            for (int j = 0; j < 4; ++j) {
                float o = acc[mi][ni][j] + bv;
                if (F32OUT) ((float*)Cout)[(size_t)(rbase + j) * N + c] = o;
                else        ((u16*)Cout)[(size_t)(rbase + j) * N + c] = f2b(o);
            }
        }
    }
}

// ---------------- flash attention (QBLK=256: 8 waves, KVBLK=64) ------------
// 32x32x16 MFMAs, S^T = mfma(K,Q). No-max softmax (exp2-domain, bounded).
// 512-thread blocks, 256 q-rows each (wave owns 32): grid 768 = exactly
// 3 blocks/CU -> 6 waves/SIMD (R11 was 2.7) AND halved logical K/V traffic
// (4 q-blocks/head re-read K/V instead of 8). R12 lesson: do NOT raise
// occupancy by shrinking tiles/multiplying blocks -- that blew the L2
// working set (FETCH 37->220 MB). kvb-seq + zero-shuffle PV (b2<->b3 V
// columns) + lane-local VALU-L (R12-verified) kept from prior rounds.
__global__ __launch_bounds__(512, 6) void attn_kernel(
    const u16* __restrict__ QKV, u16* __restrict__ ctx) {
    __shared__ u16 lK[2][64 * 64];    // K-tile [kv][d], XOR-swizzled 16B chunks
    __shared__ u16 lV[2][64 * 68];    // V^T tile [d][kv'], kv' = b2<->b3 swap, +4 pad

    int bid = blockIdx.x;
    int wg = (bid & 7) * 96 + (bid >> 3);   // XCD swizzle, nwg=768
    int bh = wg >> 2, qt = wg & 3;
    int b = bh / 12, h = bh % 12;
    int tid = threadIdx.x;
    int lane = tid & 63, wv = tid >> 6;     // wv 0..7
    int l31 = lane & 31;
    int hb = lane >> 5;

    const u16* Qb = QKV + (size_t)b * 1024 * 2304 + h * 64;
    const u16* Kb = Qb + 768;
    const u16* Vb = Qb + 1536;

    int qrow0 = qt * 256 + wv * 32;

    // Q as B-operand: lane -> col q = l31, k(d) slots
    bf16x8 qf[4];
    #pragma unroll
    for (int ks = 0; ks < 4; ++ks)
        qf[ks] = *(const bf16x8*)(Qb + (size_t)(qrow0 + l31) * 2304 + ks * 16 + hb * 8);

    f32x16 accO0 = {}, accO1 = {};   // d-blocks 0/1
    float lacc = 0.f;                // own-rows L partial (this hb's k-slots)

    // staging geometry: K = one 16B chunk per thread (512 chunks = 8 KB tile)
    int krr = tid >> 3;                          // K row 0..63
    int kcc = (tid & 7) ^ (krr & 7);             // pre-swizzled chunk col
    // V staged by threads 0..255 (2 adjacent kv rows x 8 d each), as in R11
    bool vstage = tid < 256;
    int jj0 = (tid & 31) * 2;
    int jjs = (jj0 & ~12) | ((jj0 & 4) << 1) | ((jj0 & 8) >> 1);  // b2<->b3 swap
    int d0v = ((tid >> 5) & 7) << 3;

    // ---- prologue: stage tile 0 into buffer 0 ----
    load_lds16(Kb + (size_t)krr * 2304 + kcc * 8, &lK[0][(wv << 6) << 3]);
    if (vstage) {
        bf16x8 g0 = *(const bf16x8*)(Vb + (size_t)jj0 * 2304 + d0v);
        bf16x8 g1 = *(const bf16x8*)(Vb + (size_t)(jj0 + 1) * 2304 + d0v);
        const unsigned* a0 = (const unsigned*)&g0;
        const unsigned* a1 = (const unsigned*)&g1;
        #pragma unroll
        for (int w = 0; w < 4; ++w) {
            *(unsigned*)&lV[0][(d0v + 2 * w) * 68 + jjs] =
                __builtin_amdgcn_perm(a1[w], a0[w], 0x05040100);
            *(unsigned*)&lV[0][(d0v + 2 * w + 1) * 68 + jjs] =
                __builtin_amdgcn_perm(a1[w], a0[w], 0x07060302);
        }
    }
    __syncthreads();

    int cur = 0;
    for (int t = 0; t < 16; ++t) {
        // ---- issue prefetch for tile t+1 into buffer cur^1 (early) ----
        bf16x8 nv0, nv1;
        if (t < 15) {
            size_t kt1 = (size_t)(t + 1) * 64;
            load_lds16(Kb + (kt1 + krr) * 2304 + kcc * 8, &lK[cur ^ 1][(wv << 6) << 3]);
            if (vstage) {
                nv0 = *(const bf16x8*)(Vb + (kt1 + jj0) * 2304 + d0v);
                nv1 = *(const bf16x8*)(Vb + (kt1 + jj0 + 1) * 2304 + d0v);
            }
        }

        // ---- per 32-kv half: QK -> exp2 -> PV (accs/W die each half) ----
        #pragma unroll
        for (int kvb = 0; kvb < 2; ++kvb) {
            f32x16 accs = {};
            __builtin_amdgcn_s_setprio(1);
            #pragma unroll
            for (int ks = 0; ks < 4; ++ks) {
                bf16x8 kf = *(const bf16x8*)&lK[cur][
                    (kvb * 32 + l31) * 64 + (((ks << 1) + hb) ^ (l31 & 7)) * 8];
                accs = __builtin_amdgcn_mfma_f32_32x32x16_bf16(kf, qf[ks], accs, 0, 0, 0);
            }
            __builtin_amdgcn_s_setprio(0);

            unsigned W[8];
            float ls = 0.f;
            #pragma unroll
            for (int w = 0; w < 8; ++w) {
                float e0 = hw_exp2(accs[2 * w]);
                float e1 = hw_exp2(accs[2 * w + 1]);
                ls += e0 + e1;
                W[w] = cvt_pk_bf16(e0, e1);
            }
            lacc += ls;

            __builtin_amdgcn_s_setprio(1);
            #pragma unroll
            for (int mm = 0; mm < 2; ++mm) {
                int m = kvb * 2 + mm;
                u32x4 pw;
                pw.x = W[4 * mm];     pw.y = W[4 * mm + 1];
                pw.z = W[4 * mm + 2]; pw.w = W[4 * mm + 3];
                bf16x8 pa = *(bf16x8*)&pw;
                bf16x8 vf0 = *(const bf16x8*)&lV[cur][l31 * 68 + m * 16 + hb * 8];
                bf16x8 vf1 = *(const bf16x8*)&lV[cur][(32 + l31) * 68 + m * 16 + hb * 8];
                accO0 = __builtin_amdgcn_mfma_f32_32x32x16_bf16(pa, vf0, accO0, 0, 0, 0);
                accO1 = __builtin_amdgcn_mfma_f32_32x32x16_bf16(pa, vf1, accO1, 0, 0, 0);
            }
            __builtin_amdgcn_s_setprio(0);
        }

        // ---- write-late: V(t+1) pack into lV[cur^1] at permuted columns ----
        if (t < 15 && vstage) {
            const unsigned* a0 = (const unsigned*)&nv0;
            const unsigned* a1 = (const unsigned*)&nv1;
            #pragma unroll
            for (int w = 0; w < 4; ++w) {
                *(unsigned*)&lV[cur ^ 1][(d0v + 2 * w) * 68 + jjs] =
                    __builtin_amdgcn_perm(a1[w], a0[w], 0x05040100);
                *(unsigned*)&lV[cur ^ 1][(d0v + 2 * w + 1) * 68 + jjs] =
                    __builtin_amdgcn_perm(a1[w], a0[w], 0x07060302);
            }
        }

        __syncthreads();
        cur ^= 1;
    }

    // ---- epilogue: combine L halves, redistribute, O /= L, write ctx ----
    float lsum = lacc + __shfl_xor(lacc, 32);   // L[q = l31]
    #pragma unroll
    for (int r = 0; r < 16; ++r) {
        int q = (r & 3) + 8 * (r >> 2) + hb * 4;
        float Lr = __shfl(lsum, q);             // lane q (<32) holds L[q]
        float inv = hw_rcp(Lr);
        size_t row = (size_t)(b * 1024 + qrow0 + q);
        ctx[row * 768 + h * 64 + l31]      = f2b(accO0[r] * inv);
        ctx[row * 768 + h * 64 + 32 + l31] = f2b(accO1[r] * inv);
    }
}

// ---------------- launcher ----------------
extern "C" void kernel_launch(void* const* d_in, const int* in_sizes, int n_in,
                              void* d_out, int out_size, void* d_ws, size_t ws_size,
                              hipStream_t stream) {
    const float* x  = (const float*)d_in[0];
    const float* ci = (const float*)d_in[1];
    const float* cc = (const float*)d_in[2];
    const float* Wq = (const float*)d_in[3];
    const float* bq = (const float*)d_in[4];
    const float* Wk = (const float*)d_in[5];
    const float* bk = (const float*)d_in[6];
    const float* Wv = (const float*)d_in[7];
    const float* bv = (const float*)d_in[8];
    const float* Wo = (const float*)d_in[9];
    const float* bo = (const float*)d_in[10];
    float* out = (float*)d_out;

    unsigned char* ws = (unsigned char*)d_ws;
    size_t off = 0;
    auto alloc = [&](size_t bytes) {
        void* p = ws + off;
        off += (bytes + 255) & ~(size_t)255;
        return p;
    };
    u16*   hbuf  = (u16*)  alloc((size_t)16384 * 768 * 2);
    u16*   wqkvt = (u16*)  alloc((size_t)2304 * 768 * 2);
    u16*   wot   = (u16*)  alloc((size_t)768 * 768 * 2);
    float* biasq = (float*)alloc(2304 * 4);
    u16*   qkv   = (u16*)  alloc((size_t)16384 * 2304 * 2);
    u16*   ctx   = (u16*)  alloc((size_t)16384 * 768 * 2);

    prep_hidden<<<12288, 256, 0, stream>>>(x, ci, hbuf);
    transpose_w<<<dim3(24, 24, 4), 256, 0, stream>>>(Wq, Wk, Wv, Wo, cc, wqkvt, wot);
    bias_cat<<<9, 256, 0, stream>>>(bq, bk, bv, biasq);
    gemm_bt<0><<<2304, 256, 0, stream>>>(hbuf, wqkvt, biasq, qkv, 16384, 2304, 768, 18);
    attn_kernel<<<768, 512, 0, stream>>>(qkv, ctx);
    gemm_bt<1><<<768, 256, 0, stream>>>(ctx, wot, bo, out, 16384, 768, 768, 6);
}

// Round 14
// 180.357 us; speedup vs baseline: 2.7389x; 2.7389x over previous
//
#include <hip/hip_runtime.h>
#include <hip/hip_bf16.h>

typedef unsigned short u16;
typedef short bf16x8 __attribute__((ext_vector_type(8)));
typedef float f32x4 __attribute__((ext_vector_type(4)));
typedef float f32x16 __attribute__((ext_vector_type(16)));
typedef unsigned short u16x4 __attribute__((ext_vector_type(4)));
typedef unsigned u32x4 __attribute__((ext_vector_type(4)));

// scores pre-scaled by log2(e)/8 (folded into Wq, bq) so softmax is pure exp2
#define SCALE_Q 0.18033688011112042f

__device__ __forceinline__ u16 f2b(float f) {
    __hip_bfloat16 h = __float2bfloat16(f);   // hw v_cvt (RNE) on gfx950
    return *reinterpret_cast<u16*>(&h);
}

__device__ __forceinline__ unsigned cvt_pk_bf16(float lo, float hi) {
    unsigned r;
    asm("v_cvt_pk_bf16_f32 %0, %1, %2" : "=v"(r) : "v"(lo), "v"(hi));
    return r;
}

// single-instruction exp2/rcp via BUILTINS (hazard-safe; R10's inline-asm
// version defeated TRANS wait-state insertion -> wrong values)
#define hw_exp2 __builtin_amdgcn_exp2f
#define hw_rcp  __builtin_amdgcn_rcpf

__device__ __forceinline__ void load_lds16(const void* g, void* l) {
    __builtin_amdgcn_global_load_lds(
        (const __attribute__((address_space(1))) void*)g,
        (__attribute__((address_space(3))) void*)l, 16, 0, 0);
}

// ---------------- prep: hidden * channel_importance -> bf16 ----------------
__global__ __launch_bounds__(256) void prep_hidden(
    const float* __restrict__ x, const float* __restrict__ ci, u16* __restrict__ hbuf) {
    size_t i = ((size_t)blockIdx.x * 256 + threadIdx.x) * 4;
    float4 v = *(const float4*)(x + i);
    int c = (int)(i % 768);
    u16x4 o;
    o.x = f2b(v.x * ci[c]);     o.y = f2b(v.y * ci[c + 1]);
    o.z = f2b(v.z * ci[c + 2]); o.w = f2b(v.w * ci[c + 3]);
    *(u16x4*)(hbuf + i) = o;
}

// ---------------- prep: transpose weights to [N][K] bf16 ----------------
__global__ __launch_bounds__(256) void transpose_w(
    const float* __restrict__ Wq, const float* __restrict__ Wk,
    const float* __restrict__ Wv, const float* __restrict__ Wo,
    const float* __restrict__ cc, u16* __restrict__ wqkvt, u16* __restrict__ wot) {
    __shared__ float tile[32][33];
    int z = blockIdx.z;
    const float* src = (z == 0) ? Wq : (z == 1) ? Wk : (z == 2) ? Wv : Wo;
    u16* dst = (z < 3) ? (wqkvt + (size_t)z * 768 * 768) : wot;
    int tx = threadIdx.x & 31, ty = threadIdx.x >> 5;
    int k0 = blockIdx.x * 32, n0 = blockIdx.y * 32;
    #pragma unroll
    for (int i = ty; i < 32; i += 8) {
        float v = src[(size_t)(k0 + i) * 768 + n0 + tx];
        if (z == 3) v *= cc[k0 + i];
        if (z == 0) v *= SCALE_Q;
        tile[i][tx] = v;
    }
    __syncthreads();
    #pragma unroll
    for (int i = ty; i < 32; i += 8)
        dst[(size_t)(n0 + i) * 768 + k0 + tx] = f2b(tile[tx][i]);
}

__global__ __launch_bounds__(256) void bias_cat(
    const float* __restrict__ bq, const float* __restrict__ bk,
    const float* __restrict__ bv, float* __restrict__ biasq) {
    int i = blockIdx.x * 256 + threadIdx.x;
    biasq[i] = (i < 768) ? bq[i] * SCALE_Q : (i < 1536) ? bk[i - 768] : bv[i - 1536];
}

// ---------------- GEMM: C[M][N] = A[M][K] @ Bt[N][K]^T + bias ----------------
template <int F32OUT>
__global__ __launch_bounds__(256) void gemm_bt(
    const u16* __restrict__ A, const u16* __restrict__ Bt,
    const float* __restrict__ bias, void* __restrict__ Cout,
    int M, int N, int K, int NTN) {
    __shared__ u16 lA[128 * 64];
    __shared__ u16 lB[128 * 64];
    int nwg = gridDim.x;
    int bid = blockIdx.x;
    int wg = ((nwg & 7) == 0) ? ((bid & 7) * (nwg >> 3) + (bid >> 3)) : bid;
    int mt = wg / NTN, nt = wg % NTN;
    int row0 = mt << 7, col0 = nt << 7;
    int tid = threadIdx.x;
    int lane = tid & 63, wv = tid >> 6;
    int wm = (wv >> 1) * 64, wn = (wv & 1) * 64;
    int l15 = lane & 15, hi = lane >> 4;

    f32x4 acc[4][4] = {};

    for (int kt = 0; kt < K; kt += 64) {
        __syncthreads();
        #pragma unroll
        for (int p = 0; p < 4; ++p) {
            int cl = p * 256 + tid;
            int rr = cl >> 3;
            int cc = (cl & 7) ^ (rr & 7);
            int lo = (p * 256 + (wv << 6)) << 3;
            load_lds16(A + (size_t)(row0 + rr) * K + kt + cc * 8, &lA[lo]);
            load_lds16(Bt + (size_t)(col0 + rr) * K + kt + cc * 8, &lB[lo]);
        }
        __syncthreads();
        __builtin_amdgcn_s_setprio(1);
        #pragma unroll
        for (int ks = 0; ks < 2; ++ks) {
            bf16x8 af[4], bf[4];
            #pragma unroll
            for (int i = 0; i < 4; ++i) {
                int ra = wm + i * 16 + l15;
                af[i] = *(const bf16x8*)&lA[ra * 64 + (((ks << 2) + hi) ^ (ra & 7)) * 8];
                int rb = wn + i * 16 + l15;
                bf[i] = *(const bf16x8*)&lB[rb * 64 + (((ks << 2) + hi) ^ (rb & 7)) * 8];
            }
            #pragma unroll
            for (int mi = 0; mi < 4; ++mi)
                #pragma unroll
                for (int ni = 0; ni < 4; ++ni)
                    acc[mi][ni] = __builtin_amdgcn_mfma_f32_16x16x32_bf16(
                        af[mi], bf[ni], acc[mi][ni], 0, 0, 0);
        }
        __builtin_amdgcn_s_setprio(0);
    }

    #pragma unroll
    for (int mi = 0; mi < 4; ++mi) {
        int rbase = row0 + wm + mi * 16 + hi * 4;
        #pragma unroll
        for (int ni = 0; ni < 4; ++ni) {
            int c = col0 + wn + ni * 16 + l15;
            float bv = bias[c];
            #pragma unroll
            for (int j = 0; j < 4; ++j) {
                float o = acc[mi][ni][j] + bv;
                if (F32OUT) ((float*)Cout)[(size_t)(rbase + j) * N + c] = o;
                else        ((u16*)Cout)[(size_t)(rbase + j) * N + c] = f2b(o);
            }
        }
    }
}

// ---------------- flash attention (QBLK=256: 8 waves, KVBLK=64) ------------
// 32x32x16 MFMAs, S^T = mfma(K,Q). No-max softmax (exp2-domain, bounded).
// 512-thread blocks, 256 q-rows each. __launch_bounds__(512,4): VGPR cap 128
// >= ~103 live regs -> NO SPILLS (R13's (512,6) capped at 85 -> accumulator
// spill -> 1.7 GB scratch traffic, 5x regression). 2 blocks/CU = 16 waves/CU.
// Halved logical K/V traffic vs R11 (4 q-blocks/head re-read instead of 8).
// kvb-seq + zero-shuffle PV (b2<->b3 V columns) + lane-local VALU-L.
__global__ __launch_bounds__(512, 4) void attn_kernel(
    const u16* __restrict__ QKV, u16* __restrict__ ctx) {
    __shared__ u16 lK[2][64 * 64];    // K-tile [kv][d], XOR-swizzled 16B chunks
    __shared__ u16 lV[2][64 * 68];    // V^T tile [d][kv'], kv' = b2<->b3 swap, +4 pad

    int bid = blockIdx.x;
    int wg = (bid & 7) * 96 + (bid >> 3);   // XCD swizzle, nwg=768
    int bh = wg >> 2, qt = wg & 3;
    int b = bh / 12, h = bh % 12;
    int tid = threadIdx.x;
    int lane = tid & 63, wv = tid >> 6;     // wv 0..7
    int l31 = lane & 31;
    int hb = lane >> 5;

    const u16* Qb = QKV + (size_t)b * 1024 * 2304 + h * 64;
    const u16* Kb = Qb + 768;
    const u16* Vb = Qb + 1536;

    int qrow0 = qt * 256 + wv * 32;

    // Q as B-operand: lane -> col q = l31, k(d) slots
    bf16x8 qf[4];
    #pragma unroll
    for (int ks = 0; ks < 4; ++ks)
        qf[ks] = *(const bf16x8*)(Qb + (size_t)(qrow0 + l31) * 2304 + ks * 16 + hb * 8);

    f32x16 accO0 = {}, accO1 = {};   // d-blocks 0/1
    float lacc = 0.f;                // own-rows L partial (this hb's k-slots)

    // staging geometry: K = one 16B chunk per thread (512 chunks = 8 KB tile)
    int krr = tid >> 3;                          // K row 0..63
    int kcc = (tid & 7) ^ (krr & 7);             // pre-swizzled chunk col
    // V staged by threads 0..255 (2 adjacent kv rows x 8 d each), as in R11
    bool vstage = tid < 256;
    int jj0 = (tid & 31) * 2;
    int jjs = (jj0 & ~12) | ((jj0 & 4) << 1) | ((jj0 & 8) >> 1);  // b2<->b3 swap
    int d0v = ((tid >> 5) & 7) << 3;

    // ---- prologue: stage tile 0 into buffer 0 ----
    load_lds16(Kb + (size_t)krr * 2304 + kcc * 8, &lK[0][(wv << 6) << 3]);
    if (vstage) {
        bf16x8 g0 = *(const bf16x8*)(Vb + (size_t)jj0 * 2304 + d0v);
        bf16x8 g1 = *(const bf16x8*)(Vb + (size_t)(jj0 + 1) * 2304 + d0v);
        const unsigned* a0 = (const unsigned*)&g0;
        const unsigned* a1 = (const unsigned*)&g1;
        #pragma unroll
        for (int w = 0; w < 4; ++w) {
            *(unsigned*)&lV[0][(d0v + 2 * w) * 68 + jjs] =
                __builtin_amdgcn_perm(a1[w], a0[w], 0x05040100);
            *(unsigned*)&lV[0][(d0v + 2 * w + 1) * 68 + jjs] =
                __builtin_amdgcn_perm(a1[w], a0[w], 0x07060302);
        }
    }
    __syncthreads();

    int cur = 0;
    for (int t = 0; t < 16; ++t) {
        // ---- issue prefetch for tile t+1 into buffer cur^1 (early) ----
        bf16x8 nv0, nv1;
        if (t < 15) {
            size_t kt1 = (size_t)(t + 1) * 64;
            load_lds16(Kb + (kt1 + krr) * 2304 + kcc * 8, &lK[cur ^ 1][(wv << 6) << 3]);
            if (vstage) {
                nv0 = *(const bf16x8*)(Vb + (kt1 + jj0) * 2304 + d0v);
                nv1 = *(const bf16x8*)(Vb + (kt1 + jj0 + 1) * 2304 + d0v);
            }
        }

        // ---- per 32-kv half: QK -> exp2 -> PV (accs/W die each half) ----
        #pragma unroll
        for (int kvb = 0; kvb < 2; ++kvb) {
            f32x16 accs = {};
            __builtin_amdgcn_s_setprio(1);
            #pragma unroll
            for (int ks = 0; ks < 4; ++ks) {
                bf16x8 kf = *(const bf16x8*)&lK[cur][
                    (kvb * 32 + l31) * 64 + (((ks << 1) + hb) ^ (l31 & 7)) * 8];
                accs = __builtin_amdgcn_mfma_f32_32x32x16_bf16(kf, qf[ks], accs, 0, 0, 0);
            }
            __builtin_amdgcn_s_setprio(0);

            unsigned W[8];
            float ls = 0.f;
            #pragma unroll
            for (int w = 0; w < 8; ++w) {
                float e0 = hw_exp2(accs[2 * w]);
                float e1 = hw_exp2(accs[2 * w + 1]);
                ls += e0 + e1;
                W[w] = cvt_pk_bf16(e0, e1);
            }
            lacc += ls;

            __builtin_amdgcn_s_setprio(1);
            #pragma unroll
            for (int mm = 0; mm < 2; ++mm) {
                int m = kvb * 2 + mm;
                u32x4 pw;
                pw.x = W[4 * mm];     pw.y = W[4 * mm + 1];
                pw.z = W[4 * mm + 2]; pw.w = W[4 * mm + 3];
                bf16x8 pa = *(bf16x8*)&pw;
                bf16x8 vf0 = *(const bf16x8*)&lV[cur][l31 * 68 + m * 16 + hb * 8];
                bf16x8 vf1 = *(const bf16x8*)&lV[cur][(32 + l31) * 68 + m * 16 + hb * 8];
                accO0 = __builtin_amdgcn_mfma_f32_32x32x16_bf16(pa, vf0, accO0, 0, 0, 0);
                accO1 = __builtin_amdgcn_mfma_f32_32x32x16_bf16(pa, vf1, accO1, 0, 0, 0);
            }
            __builtin_amdgcn_s_setprio(0);
        }

        // ---- write-late: V(t+1) pack into lV[cur^1] at permuted columns ----
        if (t < 15 && vstage) {
            const unsigned* a0 = (const unsigned*)&nv0;
            const unsigned* a1 = (const unsigned*)&nv1;
            #pragma unroll
            for (int w = 0; w < 4; ++w) {
                *(unsigned*)&lV[cur ^ 1][(d0v + 2 * w) * 68 + jjs] =
                    __builtin_amdgcn_perm(a1[w], a0[w], 0x05040100);
                *(unsigned*)&lV[cur ^ 1][(d0v + 2 * w + 1) * 68 + jjs] =
                    __builtin_amdgcn_perm(a1[w], a0[w], 0x07060302);
            }
        }

        __syncthreads();
        cur ^= 1;
    }

    // ---- epilogue: combine L halves, redistribute, O /= L, write ctx ----
    float lsum = lacc + __shfl_xor(lacc, 32);   // L[q = l31]
    #pragma unroll
    for (int r = 0; r < 16; ++r) {
        int q = (r & 3) + 8 * (r >> 2) + hb * 4;
        float Lr = __shfl(lsum, q);             // lane q (<32) holds L[q]
        float inv = hw_rcp(Lr);
        size_t row = (size_t)(b * 1024 + qrow0 + q);
        ctx[row * 768 + h * 64 + l31]      = f2b(accO0[r] * inv);
        ctx[row * 768 + h * 64 + 32 + l31] = f2b(accO1[r] * inv);
    }
}

// ---------------- launcher ----------------
extern "C" void kernel_launch(void* const* d_in, const int* in_sizes, int n_in,
                              void* d_out, int out_size, void* d_ws, size_t ws_size,
                              hipStream_t stream) {
    const float* x  = (const float*)d_in[0];
    const float* ci = (const float*)d_in[1];
    const float* cc = (const float*)d_in[2];
    const float* Wq = (const float*)d_in[3];
    const float* bq = (const float*)d_in[4];
    const float* Wk = (const float*)d_in[5];
    const float* bk = (const float*)d_in[6];
    const float* Wv = (const float*)d_in[7];
    const float* bv = (const float*)d_in[8];
    const float* Wo = (const float*)d_in[9];
    const float* bo = (const float*)d_in[10];
    float* out = (float*)d_out;

    unsigned char* ws = (unsigned char*)d_ws;
    size_t off = 0;
    auto alloc = [&](size_t bytes) {
        void* p = ws + off;
        off += (bytes + 255) & ~(size_t)255;
        return p;
    };
    u16*   hbuf  = (u16*)  alloc((size_t)16384 * 768 * 2);
    u16*   wqkvt = (u16*)  alloc((size_t)2304 * 768 * 2);
    u16*   wot   = (u16*)  alloc((size_t)768 * 768 * 2);
    float* biasq = (float*)alloc(2304 * 4);
    u16*   qkv   = (u16*)  alloc((size_t)16384 * 2304 * 2);
    u16*   ctx   = (u16*)  alloc((size_t)16384 * 768 * 2);

    prep_hidden<<<12288, 256, 0, stream>>>(x, ci, hbuf);
    transpose_w<<<dim3(24, 24, 4), 256, 0, stream>>>(Wq, Wk, Wv, Wo, cc, wqkvt, wot);
    bias_cat<<<9, 256, 0, stream>>>(bq, bk, bv, biasq);
    gemm_bt<0><<<2304, 256, 0, stream>>>(hbuf, wqkvt, biasq, qkv, 16384, 2304, 768, 18);
    attn_kernel<<<768, 512, 0, stream>>>(qkv, ctx);
    gemm_bt<1><<<768, 256, 0, stream>>>(ctx, wot, bo, out, 16384, 768, 768, 6);
}